// Round 2
// baseline (978.751 us; speedup 1.0000x reference)
//
#include <hip/hip_runtime.h>
#include <stdint.h>

// MoE SwiGLU top-2, MI355X. B=2,S=2048 -> T=4096 tokens; D=1024, E=8, DFF=4096.
// Plan: fp32 router (exact top-k) -> per-expert token lists (padded to 128) ->
// bf16 grouped GEMM1+3 fused (silu(xW1^T)*(xW3^T) -> h bf16) ->
// bf16 grouped GEMM2 with weighted atomicAdd combine into fp32 y.
#define T_TOK   4096
#define D_MODEL 1024
#define N_EXP   8
#define DFF_    4096
#define MAXN    4096          // per-expert list capacity (max possible)
#define MAXTILE 72            // max total row tiles: 8192/128 + 8 partials

typedef __attribute__((ext_vector_type(8))) short short8;
typedef __attribute__((ext_vector_type(4))) float f32x4;

__device__ __forceinline__ unsigned short f2bf(float f) {
  unsigned u = __float_as_uint(f);
  u += 0x7fffu + ((u >> 16) & 1u);       // RNE
  return (unsigned short)(u >> 16);
}

__device__ __forceinline__ void gld16(const void* g, void* l) {
  // async global->LDS, 16B/lane; LDS dest is wave-uniform base + lane*16.
  __builtin_amdgcn_global_load_lds(
      (const __attribute__((address_space(1))) void*)g,
      (__attribute__((address_space(3))) void*)l, 16, 0, 0);
}

// ---------------- init: zero y, zero counts ----------------
__global__ void k_init(float* __restrict__ y, int* __restrict__ cnt) {
  size_t i = (size_t)blockIdx.x * blockDim.x + threadIdx.x;
  size_t stride = (size_t)gridDim.x * blockDim.x;
  float4* y4 = (float4*)y;
  const size_t n4 = (size_t)T_TOK * D_MODEL / 4;
  float4 z; z.x = z.y = z.z = z.w = 0.f;
  for (size_t k = i; k < n4; k += stride) y4[k] = z;
  if (i < N_EXP) cnt[i] = 0;
}

// ---------------- fp32 -> bf16 weight conversion ----------------
__global__ void k_cvt(const float* __restrict__ src, unsigned short* __restrict__ dst, size_t n4) {
  size_t i = (size_t)blockIdx.x * blockDim.x + threadIdx.x;
  size_t stride = (size_t)gridDim.x * blockDim.x;
  const float4* s4 = (const float4*)src;
  for (size_t k = i; k < n4; k += stride) {
    float4 v = s4[k];
    ushort4 o;
    o.x = f2bf(v.x); o.y = f2bf(v.y); o.z = f2bf(v.z); o.w = f2bf(v.w);
    *(ushort4*)(dst + 4 * k) = o;
  }
}

// x -> bf16, plus one zeroed pad row at row index T_TOK (sentinel target)
__global__ void k_cvt_x(const float* __restrict__ src, unsigned short* __restrict__ dst) {
  const size_t n4  = (size_t)T_TOK * D_MODEL / 4;
  const size_t np4 = (size_t)(T_TOK + 1) * D_MODEL / 4;
  size_t i = (size_t)blockIdx.x * blockDim.x + threadIdx.x;
  size_t stride = (size_t)gridDim.x * blockDim.x;
  const float4* s4 = (const float4*)src;
  for (size_t k = i; k < np4; k += stride) {
    ushort4 o;
    if (k < n4) {
      float4 v = s4[k];
      o.x = f2bf(v.x); o.y = f2bf(v.y); o.z = f2bf(v.z); o.w = f2bf(v.w);
    } else {
      o.x = o.y = o.z = o.w = 0;
    }
    *(ushort4*)(dst + 4 * k) = o;
  }
}

// ---------------- router: fp32 logits, top-2, softmax, list append ----------------
// 1 wave per token; fp32 so expert selection matches the reference.
__global__ void k_router(const float* __restrict__ x, const float* __restrict__ Wg,
                         const float* __restrict__ bg, int* __restrict__ cnt,
                         int* __restrict__ tokList, float* __restrict__ wgtList) {
  int wid = (int)((blockIdx.x * blockDim.x + threadIdx.x) >> 6);   // token id
  int l = threadIdx.x & 63;
  const float* xr = x + (size_t)wid * D_MODEL;
  float acc[N_EXP];
#pragma unroll
  for (int e = 0; e < N_EXP; ++e) acc[e] = 0.f;
  for (int i = 0; i < D_MODEL / 64; ++i) {
    int c = i * 64 + l;
    float xv = xr[c];
#pragma unroll
    for (int e = 0; e < N_EXP; ++e) acc[e] += xv * Wg[e * D_MODEL + c];
  }
#pragma unroll
  for (int e = 0; e < N_EXP; ++e) {
    float v = acc[e];
    for (int off = 32; off; off >>= 1) v += __shfl_xor(v, off);
    acc[e] = v;
  }
  if (l == 0) {
    float vals[N_EXP];
#pragma unroll
    for (int e = 0; e < N_EXP; ++e) vals[e] = acc[e] + bg[e];
    int e0 = 0; float v0 = vals[0];
#pragma unroll
    for (int e = 1; e < N_EXP; ++e) if (vals[e] > v0) { v0 = vals[e]; e0 = e; }
    int e1 = -1; float v1 = -3.4e38f;
#pragma unroll
    for (int e = 0; e < N_EXP; ++e) if (e != e0 && vals[e] > v1) { v1 = vals[e]; e1 = e; }
    float t = expf(v1 - v0);               // softmax over the top-2 only
    float z = 1.f / (1.f + t);
    float w0 = z, w1 = t * z;
    int s0 = atomicAdd(&cnt[e0], 1);
    tokList[e0 * MAXN + s0] = wid; wgtList[e0 * MAXN + s0] = w0;
    int s1 = atomicAdd(&cnt[e1], 1);
    tokList[e1 * MAXN + s1] = wid; wgtList[e1 * MAXN + s1] = w1;
  }
}

// ---------------- pad lists to 128-multiple, compute row-tile offsets ----------------
__global__ void k_pad(const int* __restrict__ cnt, int* __restrict__ rto,
                      int* __restrict__ tokList, float* __restrict__ wgtList) {
  if (threadIdx.x == 0) {
    int acc = 0;
    for (int e = 0; e < N_EXP; ++e) { rto[e] = acc; acc += (cnt[e] + 127) >> 7; }
    rto[N_EXP] = acc;
  }
  for (int e = 0; e < N_EXP; ++e) {
    int c = cnt[e];
    int p = ((c + 127) >> 7) << 7;
    for (int s = c + (int)threadIdx.x; s < p; s += 256) {
      tokList[e * MAXN + s] = T_TOK;     // sentinel -> zero row of xb
      wgtList[e * MAXN + s] = 0.f;
    }
  }
}

// ---------------- grouped GEMM1+3 fused: h = silu(x W1^T) * (x W3^T), bf16 out ----------------
// grid (32 dff-tiles, 72 row-tiles), block 256 (4 waves, 2x2), tile 128x128, BK=32.
// LDS tiles chunk-major [kchunk=4][row 0..127][8 bf16] so ds_read_b128 fragment
// reads are bank-conflict-free without padding (gld16 dest must stay linear).
__global__ __launch_bounds__(256, 2) void k_gemm13(
    const unsigned short* __restrict__ xb, const unsigned short* __restrict__ w1b,
    const unsigned short* __restrict__ w3b, unsigned short* __restrict__ hbuf,
    const int* __restrict__ tokList, const int* __restrict__ rto) {
  __shared__ alignas(16) short lsA[4 * 128 * 8];
  __shared__ alignas(16) short lsB1[4 * 128 * 8];
  __shared__ alignas(16) short lsB3[4 * 128 * 8];
  __shared__ int lsTok[128];

  const int by = blockIdx.y;
  if (by >= rto[N_EXP]) return;
  int e = 0;
#pragma unroll
  for (int q = 1; q < N_EXP; ++q) if (rto[q] <= by) e = q;
  const int slot0 = (by - rto[e]) * 128;

  const int tid = threadIdx.x;
  const int w = tid >> 6, l = tid & 63;
  const int lr = l >> 4, lc = l & 15;
  const int wm = w >> 1, wn = w & 1;
  const int bx = blockIdx.x;

  if (tid < 128) lsTok[tid] = tokList[e * MAXN + slot0 + tid];
  __syncthreads();

  const char* xbB = (const char*)xb;
  const char* srcA0 = xbB + (size_t)lsTok[l] * 2048 + w * 16;
  const char* srcA1 = xbB + (size_t)lsTok[64 + l] * 2048 + w * 16;
  const size_t wbase = ((size_t)e * DFF_ + (size_t)bx * 128) * 2048;
  const char* srcB1_0 = (const char*)w1b + wbase + (size_t)l * 2048 + w * 16;
  const char* srcB1_1 = (const char*)w1b + wbase + (size_t)(64 + l) * 2048 + w * 16;
  const char* srcB3_0 = (const char*)w3b + wbase + (size_t)l * 2048 + w * 16;
  const char* srcB3_1 = (const char*)w3b + wbase + (size_t)(64 + l) * 2048 + w * 16;

  char* lsAb  = (char*)lsA  + w * 2048;
  char* lsB1b = (char*)lsB1 + w * 2048;
  char* lsB3b = (char*)lsB3 + w * 2048;

  f32x4 accA[4][4], accB[4][4];
#pragma unroll
  for (int i = 0; i < 4; ++i)
#pragma unroll
    for (int j = 0; j < 4; ++j) {
      accA[i][j] = (f32x4){0.f, 0.f, 0.f, 0.f};
      accB[i][j] = (f32x4){0.f, 0.f, 0.f, 0.f};
    }

  const short* aBase  = &lsA [lr * 1024 + (wm * 64 + lc) * 8];
  const short* b1Base = &lsB1[lr * 1024 + (wn * 64 + lc) * 8];
  const short* b3Base = &lsB3[lr * 1024 + (wn * 64 + lc) * 8];

  for (int kk = 0; kk < D_MODEL / 32; ++kk) {
    const size_t ko = (size_t)kk * 64;
    gld16(srcA0 + ko, lsAb);
    gld16(srcA1 + ko, lsAb + 1024);
    gld16(srcB1_0 + ko, lsB1b);
    gld16(srcB1_1 + ko, lsB1b + 1024);
    gld16(srcB3_0 + ko, lsB3b);
    gld16(srcB3_1 + ko, lsB3b + 1024);
    __syncthreads();                      // compiler drains vmcnt before barrier
    short8 a[4], b1[4], b3[4];
#pragma unroll
    for (int i = 0; i < 4; ++i) a[i]  = *(const short8*)(aBase + i * 128);
#pragma unroll
    for (int j = 0; j < 4; ++j) b1[j] = *(const short8*)(b1Base + j * 128);
#pragma unroll
    for (int j = 0; j < 4; ++j) b3[j] = *(const short8*)(b3Base + j * 128);
#pragma unroll
    for (int i = 0; i < 4; ++i)
#pragma unroll
      for (int j = 0; j < 4; ++j) {
        accA[i][j] = __builtin_amdgcn_mfma_f32_16x16x32_bf16(a[i], b1[j], accA[i][j], 0, 0, 0);
        accB[i][j] = __builtin_amdgcn_mfma_f32_16x16x32_bf16(a[i], b3[j], accB[i][j], 0, 0, 0);
      }
    __syncthreads();
  }

  // epilogue: silu(c1)*c3 -> bf16 h.  C/D: col=lane&15, row=(lane>>4)*4+reg.
  const size_t hcol = (size_t)bx * 128 + wn * 64 + lc;
#pragma unroll
  for (int i = 0; i < 4; ++i)
#pragma unroll
    for (int r = 0; r < 4; ++r) {
      int m = wm * 64 + i * 16 + lr * 4 + r;
      unsigned short* hrow = hbuf + ((size_t)by * 128 + m) * DFF_ + hcol;
#pragma unroll
      for (int j = 0; j < 4; ++j) {
        float c1 = accA[i][j][r], c3 = accB[i][j][r];
        float hv = c1 / (1.f + __expf(-c1)) * c3;
        hrow[j * 16] = f2bf(hv);
      }
    }
}

// ---------------- grouped GEMM2: y[tok] += w * (h W2^T) ----------------
// grid (8 d-tiles, 72 row-tiles), block 256, tile 128x128, BK=32, K=4096.
// Weighted combine via atomicAdd: each y element receives exactly 2 adds.
__global__ __launch_bounds__(256, 3) void k_gemm2(
    const unsigned short* __restrict__ hbuf, const unsigned short* __restrict__ w2b,
    float* __restrict__ y, const int* __restrict__ tokList,
    const float* __restrict__ wgtList, const int* __restrict__ rto) {
  __shared__ alignas(16) short lsA[4 * 128 * 8];
  __shared__ alignas(16) short lsB[4 * 128 * 8];
  __shared__ int lsTok[128];
  __shared__ float lsW[128];

  const int by = blockIdx.y;
  if (by >= rto[N_EXP]) return;
  int e = 0;
#pragma unroll
  for (int q = 1; q < N_EXP; ++q) if (rto[q] <= by) e = q;
  const int slot0 = (by - rto[e]) * 128;

  const int tid = threadIdx.x;
  const int w = tid >> 6, l = tid & 63;
  const int lr = l >> 4, lc = l & 15;
  const int wm = w >> 1, wn = w & 1;
  const int bx = blockIdx.x;

  if (tid < 128) {
    lsTok[tid] = tokList[e * MAXN + slot0 + tid];
    lsW[tid]   = wgtList[e * MAXN + slot0 + tid];
  }
  __syncthreads();

  const char* hB = (const char*)hbuf;
  const char* srcA0 = hB + ((size_t)by * 128 + l) * 8192 + w * 16;
  const char* srcA1 = hB + ((size_t)by * 128 + 64 + l) * 8192 + w * 16;
  const char* w2B = (const char*)w2b + ((size_t)e * D_MODEL + (size_t)bx * 128) * 8192;
  const char* srcB0 = w2B + (size_t)l * 8192 + w * 16;
  const char* srcB1 = w2B + (size_t)(64 + l) * 8192 + w * 16;

  char* lsAb = (char*)lsA + w * 2048;
  char* lsBb = (char*)lsB + w * 2048;

  f32x4 acc[4][4];
#pragma unroll
  for (int i = 0; i < 4; ++i)
#pragma unroll
    for (int j = 0; j < 4; ++j) acc[i][j] = (f32x4){0.f, 0.f, 0.f, 0.f};

  const short* aBase = &lsA[lr * 1024 + (wm * 64 + lc) * 8];
  const short* bBase = &lsB[lr * 1024 + (wn * 64 + lc) * 8];

  for (int kk = 0; kk < DFF_ / 32; ++kk) {
    const size_t ko = (size_t)kk * 64;
    gld16(srcA0 + ko, lsAb);
    gld16(srcA1 + ko, lsAb + 1024);
    gld16(srcB0 + ko, lsBb);
    gld16(srcB1 + ko, lsBb + 1024);
    __syncthreads();
    short8 a[4], b[4];
#pragma unroll
    for (int i = 0; i < 4; ++i) a[i] = *(const short8*)(aBase + i * 128);
#pragma unroll
    for (int j = 0; j < 4; ++j) b[j] = *(const short8*)(bBase + j * 128);
#pragma unroll
    for (int i = 0; i < 4; ++i)
#pragma unroll
      for (int j = 0; j < 4; ++j)
        acc[i][j] = __builtin_amdgcn_mfma_f32_16x16x32_bf16(a[i], b[j], acc[i][j], 0, 0, 0);
    __syncthreads();
  }

#pragma unroll
  for (int i = 0; i < 4; ++i)
#pragma unroll
    for (int r = 0; r < 4; ++r) {
      int m = wm * 64 + i * 16 + lr * 4 + r;
      int t = lsTok[m];
      float wv = lsW[m];
      if (t < T_TOK) {
        float* yr = y + (size_t)t * D_MODEL + (size_t)bx * 128 + wn * 64 + lc;
#pragma unroll
        for (int j = 0; j < 4; ++j)
          atomicAdd(yr + j * 16, wv * acc[i][j][r]);
      }
    }
}

// ---------------- launch ----------------
extern "C" void kernel_launch(void* const* d_in, const int* in_sizes, int n_in,
                              void* d_out, int out_size, void* d_ws, size_t ws_size,
                              hipStream_t stream) {
  const float* x  = (const float*)d_in[0];
  const float* Wg = (const float*)d_in[1];
  const float* bg = (const float*)d_in[2];
  const float* W1 = (const float*)d_in[3];
  const float* W2 = (const float*)d_in[4];
  const float* W3 = (const float*)d_in[5];
  float* y = (float*)d_out;

  char* ws = (char*)d_ws;
  size_t o = 0;
  auto alloc = [&](size_t bytes) -> char* {
    char* p = ws + o;
    o = (o + bytes + 255) & ~(size_t)255;
    return p;
  };
  unsigned short* xb   = (unsigned short*)alloc((size_t)(T_TOK + 1) * D_MODEL * 2);
  unsigned short* w1b  = (unsigned short*)alloc((size_t)N_EXP * DFF_ * D_MODEL * 2);
  unsigned short* w3b  = (unsigned short*)alloc((size_t)N_EXP * DFF_ * D_MODEL * 2);
  unsigned short* w2b  = (unsigned short*)alloc((size_t)N_EXP * D_MODEL * DFF_ * 2);
  unsigned short* hbuf = (unsigned short*)alloc((size_t)MAXTILE * 128 * DFF_ * 2);
  int*   tok = (int*)alloc((size_t)N_EXP * MAXN * 4);
  float* wgt = (float*)alloc((size_t)N_EXP * MAXN * 4);
  int*   cnt = (int*)alloc(64);
  int*   rto = (int*)alloc(64);
  (void)ws_size; (void)in_sizes; (void)n_in; (void)out_size;

  const size_t wn4 = (size_t)N_EXP * DFF_ * D_MODEL / 4;

  hipLaunchKernelGGL(k_init,  dim3(2048), dim3(256), 0, stream, y, cnt);
  hipLaunchKernelGGL(k_cvt_x, dim3(2048), dim3(256), 0, stream, x, xb);
  hipLaunchKernelGGL(k_cvt,   dim3(4096), dim3(256), 0, stream, W1, w1b, wn4);
  hipLaunchKernelGGL(k_cvt,   dim3(4096), dim3(256), 0, stream, W3, w3b, wn4);
  hipLaunchKernelGGL(k_cvt,   dim3(4096), dim3(256), 0, stream, W2, w2b, wn4);
  hipLaunchKernelGGL(k_router, dim3(T_TOK / 4), dim3(256), 0, stream, x, Wg, bg, cnt, tok, wgt);
  hipLaunchKernelGGL(k_pad,   dim3(1), dim3(256), 0, stream, cnt, rto, tok, wgt);
  hipLaunchKernelGGL(k_gemm13, dim3(32, MAXTILE), dim3(256), 0, stream, xb, w1b, w3b, hbuf, tok, rto);
  hipLaunchKernelGGL(k_gemm2,  dim3(8, MAXTILE), dim3(256), 0, stream, hbuf, w2b, y, tok, wgt, rto);
}